// Round 8
// baseline (257.371 us; speedup 1.0000x reference)
//
#include <hip/hip_runtime.h>
#include <hip/hip_bf16.h>
#include <hip/hip_cooperative_groups.h>
#include <math.h>

namespace cg = cooperative_groups;

// SupConLoss, B=4096 V=2 D=128, N=8192.
// loss = (1/N) [ sum_i log(sum_{j!=i} exp(n_i.n_j/T)) - 2*sum_b spos_b ]
// Round 18: ONE cooperative dispatch (prep -> main -> final fused).
//  - R13/R15/R17 triple: 8 barriers ~81us, 4 barriers ~90us, 0 barriers ~89us
//    => main_k's sync structure is NOT the lever; R11/R13 shape is a local
//    optimum (~23us). Budget: 42us harness fill + ~23us main + ~16us
//    prep/final/dispatch-gaps. This round attacks the 16us.
//  - fused_k = grid-strided prep + R13 main body (byte-for-byte) + final,
//    grid.sync() + threadfence at phase boundaries. Grid 528 = main's grid,
//    fits cooperative capacity (768 slots at occ 3; LDS 21.4KB).
//  - sposPart now 528 entries (one per block, 8 rows each). Final phase:
//    blocks 0..31 do the 8192 log terms; block 32 sums sposPart.
//  - Fallback: if hipLaunchCooperativeKernel is rejected, launch the proven
//    R13 3-dispatch path (kept intact below with its own 1024-entry spos).

constexpr int   Bsz   = 4096;
constexpr int   Nrows = 8192;
constexpr int   Dd    = 128;
constexpr float TEMPf = 0.07f;
constexpr float EPSN  = 1e-8f;
constexpr float SCALE = 1.4426950408889634f / 0.07f;  // log2(e)/T
constexpr float LN2   = 0.6931471805599453f;

constexpr int CHUNKS     = 32;                 // 256-col chunks
constexpr int CHUNK_COLS = Nrows / CHUNKS;     // 256
constexpr int TILES      = CHUNK_COLS / 32;    // 8 tiles of 32 cols
constexpr int ROWS_BLK   = 256;                // rows per block (4 waves x 64)
constexpr int NPAIRS     = CHUNKS * (CHUNKS + 1) / 2;  // 528
constexpr int YG         = Nrows / ROWS_BLK;   // 32 (partial planes)
constexpr int PREPBLKS   = Bsz / 4;            // 1024 (fallback path)
constexpr int PREPWAVES  = NPAIRS * 4;         // 2112 (fused path)

typedef __attribute__((ext_vector_type(8)))  short bf16x8;   // 8 bf16 = 4 VGPRs
typedef __attribute__((ext_vector_type(16))) float floatx16; // MFMA 32x32 C/D

// Fragment-major n: row r = g*32+lo stores its 256 B as pieces at
// g*8192 + kc*1024 + hi*512 + lo*16. Wave fragment load (g,kc) =
// base + g*8192 + kc*1024 + lane*16 — one coalesced 1 KB access, and the
// global_load_lds hardware placement (lds_base + lane*16) reproduces it in LDS.

// ws layout (bytes):
//   0x000000  nF   fragment-major bf16 n   2 MB
//   0x200000  partial f32[32][8192]        1 MB   (per-chunk col-sum planes)
//   0x300000  sposPart f32[<=1024]         4 KB
constexpr size_t OFF_PART = 0x200000;
constexpr size_t OFF_SPOS = 0x300000;

__device__ __forceinline__ void gld_lds16(const void* g, void* l) {
    __builtin_amdgcn_global_load_lds(
        (const __attribute__((address_space(1))) void*)g,
        (__attribute__((address_space(3))) void*)l, 16, 0, 0);
}

// normalize one feature row pair (views 0/1 of batch item b), write nF,
// return dt/T contribution. Wave-cooperative: lane covers k=2*lane..2*lane+1.
__device__ __forceinline__ float prep_row(const float* __restrict__ f,
                                          char* __restrict__ nF,
                                          int b, int lane) {
    const float* s0 = f + (size_t)(b * 2) * Dd;       // features[b, 0, :]
    float2 x = *(const float2*)(s0 + lane * 2);       // view 0
    float2 y = *(const float2*)(s0 + Dd + lane * 2);  // view 1
    float ss0 = x.x * x.x + x.y * x.y;
    float ss1 = y.x * y.x + y.y * y.y;
    float dt  = x.x * y.x + x.y * y.y;
    #pragma unroll
    for (int off = 32; off; off >>= 1) {
        ss0 += __shfl_xor(ss0, off);
        ss1 += __shfl_xor(ss1, off);
        dt  += __shfl_xor(dt,  off);
    }
    float inv0 = 1.0f / fmaxf(sqrtf(ss0), EPSN);
    float inv1 = 1.0f / fmaxf(sqrtf(ss1), EPSN);

    // lane holds k = 2*lane..2*lane+1 -> piece (kc=lane>>3, hi=(lane>>2)&1),
    // byte offset inside piece = (lane&3)*4
    size_t poff = (size_t)(lane >> 3) * 1024 + ((lane >> 2) & 1) * 512
                + (lane & 3) * 4;

    __hip_bfloat162 h;
    h.x = __float2bfloat16(x.x * inv0);
    h.y = __float2bfloat16(x.y * inv0);
    *(__hip_bfloat162*)(nF + (size_t)(b >> 5) * 8192 + (b & 31) * 16 + poff) = h;
    int r1 = Bsz + b;
    h.x = __float2bfloat16(y.x * inv1);
    h.y = __float2bfloat16(y.y * inv1);
    *(__hip_bfloat162*)(nF + (size_t)(r1 >> 5) * 8192 + (r1 & 31) * 16 + poff) = h;

    return dt * inv0 * inv1 / TEMPf;
}

// ===================== fused single-dispatch kernel ===========================
__global__ __launch_bounds__(256, 3)
void fused_k(const float* __restrict__ f, char* __restrict__ nF,
             float* __restrict__ partial, float* __restrict__ sposPart,
             float* __restrict__ out) {
    __shared__ char  bufs[2][8192];
    __shared__ float colred[4][256];
    __shared__ float rred[256];
    __shared__ float sredP[4];
    const int tid  = threadIdx.x;
    const int wid  = tid >> 6;
    const int lane = tid & 63;
    const int lo   = lane & 31;
    const int hi   = lane >> 5;

    // ---------------- phase 1: prep (grid-strided, 2112 waves) ----------------
    if (blockIdx.x == 0 && tid == 0) out[0] = 0.f;
    {
        int wgid = blockIdx.x * 4 + wid;               // 0..2111
        float sdt = 0.f;
        for (int b = wgid; b < Bsz; b += PREPWAVES)
            sdt += prep_row(f, nF, b, lane);
        if (lane == 0) sredP[wid] = sdt;
    }
    __syncthreads();
    if (tid == 0) sposPart[blockIdx.x] = sredP[0] + sredP[1] + sredP[2] + sredP[3];
    __threadfence();
    cg::this_grid().sync();

    // ---------------- phase 2: main (R13 body, byte-for-byte) -----------------
    // triangle decode: blockIdx.x -> (ci, cj), ci <= cj
    int p = blockIdx.x, ci = 0;
    while (p >= CHUNKS - ci) { p -= CHUNKS - ci; ci++; }
    const int cj = ci + p;

    const int rbase = ci * ROWS_BLK + wid * 64;          // wave's 64 rows
    const int cbase = cj * ROWS_BLK;                     // block's 256 cols
    const int cg0   = cj * 8;                            // first col group

    // A fragments: two 32-row groups, 8 coalesced 1 KB loads each (64 VGPRs)
    bf16x8 afrag[2][8];
    #pragma unroll
    for (int g = 0; g < 2; g++) {
        const char* ag = nF + (size_t)((rbase + g * 32) >> 5) * 8192 + lane * 16;
        #pragma unroll
        for (int kc = 0; kc < 8; kc++)
            afrag[g][kc] = *(const bf16x8*)(ag + kc * 1024);
    }

    // row-sum accumulators: slot (g,r) = row rbase + g*32 + (r&3)+8*(r>>2)+4*hi
    float rs[2][16];
    #pragma unroll
    for (int g = 0; g < 2; g++)
        #pragma unroll
        for (int r = 0; r < 16; r++) rs[g][r] = 0.f;

    // stage tile 0 (each wave DMAs fragments kc = 2*wid, 2*wid+1)
    {
        const char* g0 = nF + (size_t)cg0 * 8192;
        int kc = wid * 2;
        gld_lds16(g0 + kc * 1024 + lane * 16,       &bufs[0][kc * 1024]);
        gld_lds16(g0 + (kc + 1) * 1024 + lane * 16, &bufs[0][(kc + 1) * 1024]);
    }

    #pragma unroll 1
    for (int t = 0; t < TILES; t++) {
        // barrier: (a) tile t's DMA drained (compiler emits vmcnt(0) before
        // s_barrier), (b) all waves done reading the buffer we stage into next
        __syncthreads();
        if (t + 1 < TILES) {
            const char* gn = nF + (size_t)(cg0 + t + 1) * 8192;
            char* dst = bufs[(t + 1) & 1];
            int kc = wid * 2;
            gld_lds16(gn + kc * 1024 + lane * 16,       dst + kc * 1024);
            gld_lds16(gn + (kc + 1) * 1024 + lane * 16, dst + (kc + 1) * 1024);
        }

        const char* buf = bufs[t & 1];
        floatx16 acc0 = {}, acc1 = {};
        #pragma unroll
        for (int kc = 0; kc < 8; kc++) {
            bf16x8 bf = *(const bf16x8*)&buf[kc * 1024 + lane * 16];
            acc0 = __builtin_amdgcn_mfma_f32_32x32x16_bf16(afrag[0][kc], bf, acc0, 0, 0, 0);
            acc1 = __builtin_amdgcn_mfma_f32_32x32x16_bf16(afrag[1][kc], bf, acc1, 0, 0, 0);
        }

        // epilogue: exp2, diagonal mask (wave-uniform branch), col + row sums
        const int cb32 = cbase + t * 32;
        float cs = 0.f;
        #pragma unroll
        for (int g = 0; g < 2; g++) {
            const floatx16& acc = g ? acc1 : acc0;
            if (cb32 == rbase + g * 32) {     // only possible on diag blocks
                #pragma unroll
                for (int r = 0; r < 16; r++) {
                    float e = __builtin_amdgcn_exp2f(acc[r] * SCALE);
                    // C/D layout: col=lo, row_local=(r&3)+8*(r>>2)+4*hi
                    if (lo == ((r & 3) + 8 * (r >> 2) + 4 * hi)) e = 0.f;
                    cs += e; rs[g][r] += e;
                }
            } else {
                #pragma unroll
                for (int r = 0; r < 16; r++) {
                    float e = __builtin_amdgcn_exp2f(acc[r] * SCALE);
                    cs += e; rs[g][r] += e;
                }
            }
        }
        cs += __shfl_xor(cs, 32);             // fold the two row-half lanes
        if (hi == 0) colred[wid][t * 32 + lo] = cs;
    }

    // off-diag: reduce row sums across the 32 column-lanes, stage to LDS strip
    if (ci != cj) {
        #pragma unroll
        for (int g = 0; g < 2; g++) {
            #pragma unroll
            for (int r = 0; r < 16; r++) {
                float v = rs[g][r];
                v += __shfl_xor(v, 1);
                v += __shfl_xor(v, 2);
                v += __shfl_xor(v, 4);
                v += __shfl_xor(v, 8);
                v += __shfl_xor(v, 16);
                if (lo == r)
                    rred[wid * 64 + g * 32 + ((r & 3) + 8 * (r >> 2) + 4 * hi)] = v;
            }
        }
    }

    __syncthreads();
    // col sums of this 256-row stripe -> plane ci, cols of chunk cj
    float v = colred[0][tid] + colred[1][tid] + colred[2][tid] + colred[3][tid];
    partial[(size_t)ci * Nrows + cbase + tid] = v;
    // row sums (== transposed block's col sums) -> plane cj, rows of chunk ci
    if (ci != cj)
        partial[(size_t)cj * Nrows + ci * ROWS_BLK + tid] = rred[tid];

    __threadfence();
    cg::this_grid().sync();

    // ---------------- phase 3: final --------------------------------------------
    if (blockIdx.x < YG) {
        int r = blockIdx.x * 256 + tid;
        float se = 0.f;
        #pragma unroll
        for (int q = 0; q < YG; q++) se += partial[(size_t)q * Nrows + r];
        float acc = __builtin_amdgcn_logf(se) * LN2;   // v_log_f32 is log2
        #pragma unroll
        for (int off = 32; off; off >>= 1) acc += __shfl_xor(acc, off);
        if ((tid & 63) == 0) rred[(tid >> 6)] = acc;   // reuse rred as scratch
        __syncthreads();
        if (tid == 0)
            atomicAdd(out, (rred[0] + rred[1] + rred[2] + rred[3]) / (float)Nrows);
    } else if (blockIdx.x == YG) {
        // sum the 528 sposPart entries
        float s = sposPart[tid] + sposPart[tid + 256]
                + (tid < NPAIRS - 512 ? sposPart[tid + 512] : 0.f);
        #pragma unroll
        for (int off = 32; off; off >>= 1) s += __shfl_xor(s, off);
        if ((tid & 63) == 0) rred[(tid >> 6)] = s;
        __syncthreads();
        if (tid == 0)
            atomicAdd(out, -2.f * (rred[0] + rred[1] + rred[2] + rred[3]) / (float)Nrows);
    }
}

// ===================== fallback: proven R13 3-dispatch path ===================
__global__ void prep_k(const float* __restrict__ f,
                       char* __restrict__ nF,
                       float* __restrict__ sposPart,
                       float* __restrict__ out) {
    __shared__ float sred[4];
    int tid  = threadIdx.x;
    int wid  = tid >> 6;
    int lane = tid & 63;
    int b    = blockIdx.x * 4 + wid;
    if (blockIdx.x == 0 && tid == 0) out[0] = 0.f;
    float sdt = prep_row(f, nF, b, lane);
    if (lane == 0) sred[wid] = sdt;
    __syncthreads();
    if (tid == 0) sposPart[blockIdx.x] = sred[0] + sred[1] + sred[2] + sred[3];
}

__global__ __launch_bounds__(256, 3)
void main_k(const char* __restrict__ nF, float* __restrict__ partial) {
    __shared__ char  bufs[2][8192];
    __shared__ float colred[4][256];
    __shared__ float rred[256];
    const int tid  = threadIdx.x;
    const int wid  = tid >> 6;
    const int lane = tid & 63;
    const int lo   = lane & 31;
    const int hi   = lane >> 5;

    int p = blockIdx.x, ci = 0;
    while (p >= CHUNKS - ci) { p -= CHUNKS - ci; ci++; }
    const int cj = ci + p;

    const int rbase = ci * ROWS_BLK + wid * 64;
    const int cbase = cj * ROWS_BLK;
    const int cg0   = cj * 8;

    bf16x8 afrag[2][8];
    #pragma unroll
    for (int g = 0; g < 2; g++) {
        const char* ag = nF + (size_t)((rbase + g * 32) >> 5) * 8192 + lane * 16;
        #pragma unroll
        for (int kc = 0; kc < 8; kc++)
            afrag[g][kc] = *(const bf16x8*)(ag + kc * 1024);
    }

    float rs[2][16];
    #pragma unroll
    for (int g = 0; g < 2; g++)
        #pragma unroll
        for (int r = 0; r < 16; r++) rs[g][r] = 0.f;

    {
        const char* g0 = nF + (size_t)cg0 * 8192;
        int kc = wid * 2;
        gld_lds16(g0 + kc * 1024 + lane * 16,       &bufs[0][kc * 1024]);
        gld_lds16(g0 + (kc + 1) * 1024 + lane * 16, &bufs[0][(kc + 1) * 1024]);
    }

    #pragma unroll 1
    for (int t = 0; t < TILES; t++) {
        __syncthreads();
        if (t + 1 < TILES) {
            const char* gn = nF + (size_t)(cg0 + t + 1) * 8192;
            char* dst = bufs[(t + 1) & 1];
            int kc = wid * 2;
            gld_lds16(gn + kc * 1024 + lane * 16,       dst + kc * 1024);
            gld_lds16(gn + (kc + 1) * 1024 + lane * 16, dst + (kc + 1) * 1024);
        }

        const char* buf = bufs[t & 1];
        floatx16 acc0 = {}, acc1 = {};
        #pragma unroll
        for (int kc = 0; kc < 8; kc++) {
            bf16x8 bf = *(const bf16x8*)&buf[kc * 1024 + lane * 16];
            acc0 = __builtin_amdgcn_mfma_f32_32x32x16_bf16(afrag[0][kc], bf, acc0, 0, 0, 0);
            acc1 = __builtin_amdgcn_mfma_f32_32x32x16_bf16(afrag[1][kc], bf, acc1, 0, 0, 0);
        }

        const int cb32 = cbase + t * 32;
        float cs = 0.f;
        #pragma unroll
        for (int g = 0; g < 2; g++) {
            const floatx16& acc = g ? acc1 : acc0;
            if (cb32 == rbase + g * 32) {
                #pragma unroll
                for (int r = 0; r < 16; r++) {
                    float e = __builtin_amdgcn_exp2f(acc[r] * SCALE);
                    if (lo == ((r & 3) + 8 * (r >> 2) + 4 * hi)) e = 0.f;
                    cs += e; rs[g][r] += e;
                }
            } else {
                #pragma unroll
                for (int r = 0; r < 16; r++) {
                    float e = __builtin_amdgcn_exp2f(acc[r] * SCALE);
                    cs += e; rs[g][r] += e;
                }
            }
        }
        cs += __shfl_xor(cs, 32);
        if (hi == 0) colred[wid][t * 32 + lo] = cs;
    }

    if (ci != cj) {
        #pragma unroll
        for (int g = 0; g < 2; g++) {
            #pragma unroll
            for (int r = 0; r < 16; r++) {
                float v = rs[g][r];
                v += __shfl_xor(v, 1);
                v += __shfl_xor(v, 2);
                v += __shfl_xor(v, 4);
                v += __shfl_xor(v, 8);
                v += __shfl_xor(v, 16);
                if (lo == r)
                    rred[wid * 64 + g * 32 + ((r & 3) + 8 * (r >> 2) + 4 * hi)] = v;
            }
        }
    }

    __syncthreads();
    float v = colred[0][tid] + colred[1][tid] + colred[2][tid] + colred[3][tid];
    partial[(size_t)ci * Nrows + cbase + tid] = v;
    if (ci != cj)
        partial[(size_t)cj * Nrows + ci * ROWS_BLK + tid] = rred[tid];
}

__global__ __launch_bounds__(256)
void final_k(const float* __restrict__ partial, const float* __restrict__ sposPart,
             float* __restrict__ out) {
    __shared__ float red[4];
    int tid = threadIdx.x;
    int r = blockIdx.x * 256 + tid;
    float se = 0.f;
    #pragma unroll
    for (int p = 0; p < YG; p++) se += partial[(size_t)p * Nrows + r];
    float acc = __builtin_amdgcn_logf(se) * LN2;
    if (tid < 32) acc -= 2.f * sposPart[blockIdx.x * 32 + tid];
    #pragma unroll
    for (int off = 32; off; off >>= 1) acc += __shfl_xor(acc, off);
    if ((tid & 63) == 0) red[tid >> 6] = acc;
    __syncthreads();
    if (tid == 0)
        atomicAdd(out, (red[0] + red[1] + red[2] + red[3]) / (float)Nrows);
}

extern "C" void kernel_launch(void* const* d_in, const int* in_sizes, int n_in,
                              void* d_out, int out_size, void* d_ws, size_t ws_size,
                              hipStream_t stream) {
    const float* f = (const float*)d_in[0];
    char* ws = (char*)d_ws;
    char*  nF       = ws;
    float* partial  = (float*)(ws + OFF_PART);
    float* sposPart = (float*)(ws + OFF_SPOS);
    float* outp     = (float*)d_out;

    void* args[] = {(void*)&f, (void*)&nF, (void*)&partial, (void*)&sposPart,
                    (void*)&outp};
    hipError_t err = hipLaunchCooperativeKernel(
        (const void*)fused_k, dim3(NPAIRS), dim3(256), args, 0, stream);
    if (err != hipSuccess) {
        // fallback: proven R13 3-dispatch path
        prep_k<<<PREPBLKS, 256, 0, stream>>>(f, nF, sposPart, outp);
        main_k<<<NPAIRS, 256, 0, stream>>>(nF, partial);
        final_k<<<Nrows / 256, 256, 0, stream>>>(partial, sposPart, outp);
    }
}

// Round 9
// 78.841 us; speedup vs baseline: 3.2644x; 3.2644x over previous
//
#include <hip/hip_runtime.h>
#include <hip/hip_bf16.h>
#include <math.h>

// SupConLoss, B=4096 V=2 D=128, N=8192.
// loss = (1/N) [ sum_i log(sum_{j!=i} exp(n_i.n_j/T)) - 2*sum_b spos_b ]
// Round 19: REVERT to the harness-verified session best (R11 structure,
// 78.3us prior session / 80.1us this session).
//  - Nine measurements this session: R11=80.1, R13(triangle)=81.2 (tied),
//    R12=87, R15=90, R17=89, R14=124, R16=124, R18(cooperative fusion)=257.
//    Every structural attack on {main-loop sync, occupancy, dispatch fusion}
//    regressed or nulled.
//  - Budget model (stable across all rounds): 42us harness workspace fill
//    (untouchable) + ~23us latency-bound main_k (local optimum here) +
//    ~15us prep/final/gaps (fusion attempts poisoned regalloc: VGPR-84
//    signature in R14/R16/R18).
//  - This kernel: m97-pattern main kernel.
//    * B tiles staged via __builtin_amdgcn_global_load_lds width=16 (async
//      DMA, no VGPR round-trip), fragment-major nF: DMA lane order ==
//      fragment lane order (no swizzle).
//    * double-buffered 8 KB tiles, ONE barrier per tile (compiler-managed
//      vmcnt; every hand-rolled variant spilled or regressed).
//    * column-sum accumulation (row-sum == col-sum by symmetry): 1 scalar
//      per lane per tile.
//    * 3 dispatches; NO tickets/fences (prior session R3/R10: +7..50us),
//      NO cooperative launch (R18: +177us).

constexpr int   Bsz   = 4096;
constexpr int   Nrows = 8192;
constexpr int   Dd    = 128;
constexpr float TEMPf = 0.07f;
constexpr float EPSN  = 1e-8f;
constexpr float SCALE = 1.4426950408889634f / 0.07f;  // log2(e)/T
constexpr float LN2   = 0.6931471805599453f;

constexpr int CHUNKS     = 32;                 // col chunks (grid.x)
constexpr int CHUNK_COLS = Nrows / CHUNKS;     // 256
constexpr int TILES      = CHUNK_COLS / 32;    // 8 tiles of 32 cols
constexpr int ROWS_BLK   = 256;                // rows per block (4 waves x 64)
constexpr int YG         = Nrows / ROWS_BLK;   // 32 (grid.y)
constexpr int PREPBLKS   = Bsz / 4;            // 1024

typedef __attribute__((ext_vector_type(8)))  short bf16x8;   // 8 bf16 = 4 VGPRs
typedef __attribute__((ext_vector_type(16))) float floatx16; // MFMA 32x32 C/D

// Fragment-major n: row r = g*32+lo stores its 256 B as pieces at
// g*8192 + kc*1024 + hi*512 + lo*16. Wave fragment load (g,kc) =
// base + g*8192 + kc*1024 + lane*16 — one coalesced 1 KB access, and the
// global_load_lds hardware placement (lds_base + lane*16) reproduces it in LDS.

// ws layout (bytes):
//   0x000000  nF   fragment-major bf16 n   2 MB
//   0x200000  partial f32[32][8192]        1 MB   (col sums per row-group)
//   0x300000  sposPart f32[1024]           4 KB
constexpr size_t OFF_PART = 0x200000;
constexpr size_t OFF_SPOS = 0x300000;

__device__ __forceinline__ void gld_lds16(const void* g, void* l) {
    __builtin_amdgcn_global_load_lds(
        (const __attribute__((address_space(1))) void*)g,
        (__attribute__((address_space(3))) void*)l, 16, 0, 0);
}

// ------------- prep: normalize both views -> nF + per-block spos sums ----------
__global__ void prep_k(const float* __restrict__ f,
                       char* __restrict__ nF,
                       float* __restrict__ sposPart,
                       float* __restrict__ out) {
    __shared__ float sred[4];
    int tid  = threadIdx.x;
    int wid  = tid >> 6;
    int lane = tid & 63;
    int b    = blockIdx.x * 4 + wid;
    if (blockIdx.x == 0 && tid == 0) out[0] = 0.f;   // final_k accumulates

    const float* s0 = f + (size_t)(b * 2) * Dd;       // features[b, 0, :]
    float2 x = *(const float2*)(s0 + lane * 2);       // view 0
    float2 y = *(const float2*)(s0 + Dd + lane * 2);  // view 1
    float ss0 = x.x * x.x + x.y * x.y;
    float ss1 = y.x * y.x + y.y * y.y;
    float dt  = x.x * y.x + x.y * y.y;
    #pragma unroll
    for (int off = 32; off; off >>= 1) {
        ss0 += __shfl_xor(ss0, off);
        ss1 += __shfl_xor(ss1, off);
        dt  += __shfl_xor(dt,  off);
    }
    float inv0 = 1.0f / fmaxf(sqrtf(ss0), EPSN);
    float inv1 = 1.0f / fmaxf(sqrtf(ss1), EPSN);

    // lane holds k = 2*lane..2*lane+1 -> piece (kc=lane>>3, hi=(lane>>2)&1),
    // byte offset inside piece = (lane&3)*4
    size_t poff = (size_t)(lane >> 3) * 1024 + ((lane >> 2) & 1) * 512
                + (lane & 3) * 4;

    __hip_bfloat162 h;
    h.x = __float2bfloat16(x.x * inv0);
    h.y = __float2bfloat16(x.y * inv0);
    *(__hip_bfloat162*)(nF + (size_t)(b >> 5) * 8192 + (b & 31) * 16 + poff) = h;
    int r1 = Bsz + b;
    h.x = __float2bfloat16(y.x * inv1);
    h.y = __float2bfloat16(y.y * inv1);
    *(__hip_bfloat162*)(nF + (size_t)(r1 >> 5) * 8192 + (r1 & 31) * 16 + poff) = h;

    if (lane == 0) sred[wid] = dt * inv0 * inv1 / TEMPf;
    __syncthreads();
    if (tid == 0) sposPart[blockIdx.x] = sred[0] + sred[1] + sred[2] + sred[3];
}

// ------------- main: async-LDS GEMM + exp2 + column sums -----------------------
// Grid (32 chunks, 32 row-groups), 256 thr = 4 waves. Wave: 64 rows x 32-col
// tiles. B tile (8 KB) double-buffered via global_load_lds (2 instrs/wave),
// one barrier per tile. Column sums (== row sums by symmetry): one scalar per
// lane per tile -> LDS strip -> coalesced partial[gy][cbase..+255] store.
__global__ __launch_bounds__(256, 3)
void main_k(const char* __restrict__ nF, float* __restrict__ partial) {
    __shared__ char  bufs[2][8192];
    __shared__ float colred[4][256];
    const int tid  = threadIdx.x;
    const int wid  = tid >> 6;
    const int lane = tid & 63;
    const int lo   = lane & 31;
    const int hi   = lane >> 5;
    const int gy   = blockIdx.y;
    const int rbase = gy * ROWS_BLK + wid * 64;          // wave's 64 rows
    const int cbase = blockIdx.x * CHUNK_COLS;           // 256-aligned
    const int cg0   = cbase >> 5;                        // first col group

    // A fragments: two 32-row groups, 8 coalesced 1 KB loads each (64 VGPRs)
    bf16x8 afrag[2][8];
    #pragma unroll
    for (int s = 0; s < 2; s++) {
        const char* ag = nF + (size_t)((rbase + s * 32) >> 5) * 8192 + lane * 16;
        #pragma unroll
        for (int kc = 0; kc < 8; kc++)
            afrag[s][kc] = *(const bf16x8*)(ag + kc * 1024);
    }

    // stage tile 0 (each wave DMAs fragments kc = 2*wid, 2*wid+1)
    {
        const char* g0 = nF + (size_t)cg0 * 8192;
        int kc = wid * 2;
        gld_lds16(g0 + kc * 1024 + lane * 16,       &bufs[0][kc * 1024]);
        gld_lds16(g0 + (kc + 1) * 1024 + lane * 16, &bufs[0][(kc + 1) * 1024]);
    }

    floatx16 zero = {};

    #pragma unroll 1
    for (int t = 0; t < TILES; t++) {
        // barrier: (a) tile t's DMA drained (compiler emits vmcnt(0) before
        // s_barrier), (b) all waves done reading the buffer we stage into next
        __syncthreads();
        if (t + 1 < TILES) {
            const char* gn = nF + (size_t)(cg0 + t + 1) * 8192;
            char* dst = bufs[(t + 1) & 1];
            int kc = wid * 2;
            gld_lds16(gn + kc * 1024 + lane * 16,       dst + kc * 1024);
            gld_lds16(gn + (kc + 1) * 1024 + lane * 16, dst + (kc + 1) * 1024);
        }

        const char* buf = bufs[t & 1];
        floatx16 acc0 = zero, acc1 = zero;
        #pragma unroll
        for (int kc = 0; kc < 8; kc++) {
            bf16x8 bf = *(const bf16x8*)&buf[kc * 1024 + lane * 16];
            acc0 = __builtin_amdgcn_mfma_f32_32x32x16_bf16(afrag[0][kc], bf, acc0, 0, 0, 0);
            acc1 = __builtin_amdgcn_mfma_f32_32x32x16_bf16(afrag[1][kc], bf, acc1, 0, 0, 0);
        }

        // epilogue: exp2, diagonal mask (wave-uniform branch), COLUMN sums
        const int cb32 = cbase + t * 32;
        float cs = 0.f;
        #pragma unroll
        for (int s = 0; s < 2; s++) {
            const floatx16& acc = s ? acc1 : acc0;
            if (cb32 == rbase + s * 32) {     // taken <=1 of 16 (s,t) combos
                #pragma unroll
                for (int r = 0; r < 16; r++) {
                    float e = __builtin_amdgcn_exp2f(acc[r] * SCALE);
                    // C/D layout: col=lo, row_local=(r&3)+8*(r>>2)+4*hi
                    if (lo == ((r & 3) + 8 * (r >> 2) + 4 * hi)) e = 0.f;
                    cs += e;
                }
            } else {
                #pragma unroll
                for (int r = 0; r < 16; r++)
                    cs += __builtin_amdgcn_exp2f(acc[r] * SCALE);
            }
        }
        cs += __shfl_xor(cs, 32);             // fold the two row-half lanes
        if (hi == 0) colred[wid][t * 32 + lo] = cs;
    }

    __syncthreads();
    // cross-wave: block's col sums over its 256-row stripe, coalesced store
    float v = colred[0][tid] + colred[1][tid] + colred[2][tid] + colred[3][tid];
    partial[(size_t)gy * Nrows + cbase + tid] = v;
}

// ------------- finalize: 32 blocks; atomicAdd the scalar -----------------------
// se[r] = sum_gy partial[gy][r]  (column sum == row sum of exp matrix)
__global__ __launch_bounds__(256)
void final_k(const float* __restrict__ partial, const float* __restrict__ sposPart,
             float* __restrict__ out) {
    __shared__ float red[4];
    int tid = threadIdx.x;
    int r = blockIdx.x * 256 + tid;
    float se = 0.f;
    #pragma unroll
    for (int p = 0; p < YG; p++) se += partial[(size_t)p * Nrows + r];
    float acc = __builtin_amdgcn_logf(se) * LN2;   // v_log_f32 is log2
    if (tid < 32) acc -= 2.f * sposPart[blockIdx.x * 32 + tid];
    #pragma unroll
    for (int off = 32; off; off >>= 1) acc += __shfl_xor(acc, off);
    if ((tid & 63) == 0) red[tid >> 6] = acc;
    __syncthreads();
    if (tid == 0)
        atomicAdd(out, (red[0] + red[1] + red[2] + red[3]) / (float)Nrows);
}

extern "C" void kernel_launch(void* const* d_in, const int* in_sizes, int n_in,
                              void* d_out, int out_size, void* d_ws, size_t ws_size,
                              hipStream_t stream) {
    const float* f = (const float*)d_in[0];
    char* ws = (char*)d_ws;
    char* nF        = ws;
    float* partial  = (float*)(ws + OFF_PART);
    float* sposPart = (float*)(ws + OFF_SPOS);

    prep_k<<<PREPBLKS, 256, 0, stream>>>(f, nF, sposPart, (float*)d_out);
    dim3 grid(CHUNKS, YG);
    main_k<<<grid, 256, 0, stream>>>(nF, partial);
    final_k<<<Nrows / 256, 256, 0, stream>>>(partial, sposPart, (float*)d_out);
}